// Round 10
// baseline (325.903 us; speedup 1.0000x reference)
//
#include <hip/hip_runtime.h>
#include <math.h>

#define NBLK 256   // mega grid: one block per CU, all co-resident

// Workspace float offsets
#define OF_PW     0          // 128*8 fp32
#define OF_STATQ  1024       // 256
#define OF_STATK  1280       // 256
#define OF_STATG1 1536       // 256
#define OF_STATH  1792       // 16
#define OF_UMAXP  1808       // 512
#define OF_UMAXN  2320       // 512
#define OF_BAR    2832       // 2 unsigned (zeroed by cayley each launch)
#define OF_WQT    4096       // bf16 [n][k] weights, 8192 floats each
#define OF_WKT    12288
#define OF_WVT    20480
#define OF_WG1T   28672
#define OF_PTMIT  36864
#define OF_QW     65536      // N*8
#define OF_KW     327680     // N*8
#define OF_GATE   589824     // N*8
#define OF_G1     1048576    // N*128
#define OF_V      5242880    // N*128

typedef short bf16x8 __attribute__((ext_vector_type(8)));
typedef float f32x4  __attribute__((ext_vector_type(4)));

#define LSTR 136   // bf16 LDS row stride for full B / bnS (272 B)
#define BHS  72    // bf16 LDS row stride for half-K B tiles (144 B)

__device__ __forceinline__ unsigned f2bf(float f) {
  unsigned u = __float_as_uint(f);
  return (u + 0x7fffu + ((u >> 16) & 1u)) >> 16;
}
__device__ __forceinline__ float bf2f(short s) {
  return __uint_as_float(((unsigned)(unsigned short)s) << 16);
}
__device__ __forceinline__ unsigned fenc(float f) {
  unsigned b = __float_as_uint(f);
  return (b & 0x80000000u) ? ~b : (b | 0x80000000u);
}
__device__ __forceinline__ float fdec(unsigned u) {
  unsigned b = (u & 0x80000000u) ? (u & 0x7fffffffu) : ~u;
  return __uint_as_float(b);
}
__device__ __forceinline__ bf16x8 pack_bf8(float4 a, float4 b) {
  bf16x8 r;
  r[0] = (short)f2bf(a.x); r[1] = (short)f2bf(a.y);
  r[2] = (short)f2bf(a.z); r[3] = (short)f2bf(a.w);
  r[4] = (short)f2bf(b.x); r[5] = (short)f2bf(b.y);
  r[6] = (short)f2bf(b.z); r[7] = (short)f2bf(b.w);
  return r;
}
__device__ __forceinline__ float fetch_asym(const float* M, int r, int c) {
  return (c > r) ? M[r*128 + c] : ((c < r) ? -M[c*128 + r] : 0.f);
}

// full B [128][128] bf16 global -> LDS [128][LSTR]; 512 threads, 4 uint4 each
__device__ __forceinline__ void stageB512(short* dst, const short* __restrict__ src, int tid) {
  #pragma unroll
  for (int it = 0; it < 4; ++it) {
    int q = it*512 + tid; int r = q >> 4, c8 = q & 15;
    *(uint4*)&dst[r*LSTR + c8*8] = *(const uint4*)&src[r*128 + c8*8];
  }
}
// half-K B tile [128 n][64 k] -> LDS [128][BHS].
// 128 rows x 64 shorts = 1024 uint4 chunks -> each of 512 threads copies TWO.
// (round-8/9 bug: copied only one -> shorts 32..63 of every row were stale LDS)
__device__ __forceinline__ void stageBh(short* Bh, const short* __restrict__ src, int koff, int tid) {
  #pragma unroll
  for (int it = 0; it < 2; ++it) {
    int q = it*512 + tid;
    int r = q >> 3, c8 = q & 7;
    *(uint4*)&Bh[r*BHS + c8*8] = *(const uint4*)&src[r*128 + koff + c8*8];
  }
}

__device__ __forceinline__ void gemm8_lds(const short* Bl, const bf16x8* af,
                                          f32x4* out, int l15, int quad)
{
  #pragma unroll
  for (int nt = 0; nt < 8; ++nt) {
    f32x4 ac = {0.f, 0.f, 0.f, 0.f};
    #pragma unroll
    for (int ks = 0; ks < 4; ++ks) {
      bf16x8 bf = *(const bf16x8*)&Bl[(nt*16 + l15)*LSTR + ks*32 + quad*8];
      ac = __builtin_amdgcn_mfma_f32_16x16x32_bf16(af[ks], bf, ac, 0, 0, 0);
    }
    out[nt] = ac;
  }
}
// accumulate one K-half (h=0: af2[0..1] vs koff 0 ; h=1: af2[2..3] vs koff 64)
__device__ __forceinline__ void gemmHalf(const short* Bh, const bf16x8* af2,
                                         f32x4* acc, int h, int l15, int quad)
{
  #pragma unroll
  for (int nt = 0; nt < 8; ++nt) {
    f32x4 ac = acc[nt];
    #pragma unroll
    for (int kh = 0; kh < 2; ++kh) {
      bf16x8 bf = *(const bf16x8*)&Bh[(nt*16 + l15)*BHS + kh*32 + quad*8];
      ac = __builtin_amdgcn_mfma_f32_16x16x32_bf16(af2[h*2 + kh], bf, ac, 0, 0, 0);
    }
    acc[nt] = ac;
  }
}

// Grid barrier: all NBLK blocks co-resident (1 block/CU by launch bounds).
__device__ __forceinline__ void gridbar(unsigned* cnt, unsigned target) {
  __syncthreads();
  if (threadIdx.x == 0) {
    __threadfence();
    __hip_atomic_fetch_add(cnt, 1u, __ATOMIC_RELAXED, __HIP_MEMORY_SCOPE_AGENT);
    while (__hip_atomic_load(cnt, __ATOMIC_RELAXED, __HIP_MEMORY_SCOPE_AGENT) < target)
      __builtin_amdgcn_s_sleep(2);
    __threadfence();
  }
  __syncthreads();
}

// ---------------------------------------------------------------------------
// cayley: preprocessing + zero stats/barrier region.
__global__ __launch_bounds__(256) void cayley(const float* __restrict__ Sp,
    const float* __restrict__ Ww1,
    const float* __restrict__ Wq, const float* __restrict__ Wk,
    const float* __restrict__ Wv, const float* __restrict__ Wg1,
    short* __restrict__ WqT, short* __restrict__ WkT,
    short* __restrict__ WvT, short* __restrict__ Wg1T,
    short* __restrict__ PTmIT, float* __restrict__ PW,
    float* __restrict__ statz)
{
  __shared__ short Ssh[128*LSTR];
  __shared__ float x0[128], x1[128];
  int bx = blockIdx.x, tid = threadIdx.x;
  if (bx >= 64) {
    if (bx < 80) {
      int idx = bx - 64, widx = idx >> 2, qr = idx & 3;
      const float* src = (widx == 0) ? Wq : (widx == 1) ? Wk : (widx == 2) ? Wv : Wg1;
      short* dst = (widx == 0) ? WqT : (widx == 1) ? WkT : (widx == 2) ? WvT : Wg1T;
      const float4* s4 = (const float4*)src;
      #pragma unroll
      for (int it = 0; it < 4; ++it) {
        int q = it*256 + tid; int k = qr*32 + (q >> 5), n4 = q & 31;
        float4 v = s4[k*32 + n4];
        dst[(n4*4+0)*128 + k] = (short)f2bf(v.x);
        dst[(n4*4+1)*128 + k] = (short)f2bf(v.y);
        dst[(n4*4+2)*128 + k] = (short)f2bf(v.z);
        dst[(n4*4+3)*128 + k] = (short)f2bf(v.w);
      }
    } else {
      #pragma unroll
      for (int it = 0; it < 8; ++it) {
        int idx = it*256 + tid;
        if (idx < 1812) statz[idx] = 0.f;   // stats + umax + barrier words
      }
    }
    return;
  }
  int c0 = bx*2, c1 = c0 + 1;
  #pragma unroll 8
  for (int it = 0; it < 64; ++it) {
    int idx = it*256 + tid; int i = idx >> 7, j = idx & 127;
    Ssh[i*LSTR + j] = (short)f2bf(fetch_asym(Sp, i, j));
  }
  if (tid < 128) {
    x0[tid] = (tid == c0) ? 1.f : 0.f;
    x1[tid] = (tid == c1) ? 1.f : 0.f;
  }
  __syncthreads();
  int i = tid >> 1, h = tid & 1;
  const short* srow = &Ssh[i*LSTR + h*64];
  for (int t = 0; t < 16; ++t) {
    float a0 = 0.f, a1 = 0.f;
    #pragma unroll
    for (int jq = 0; jq < 16; ++jq) {
      short4 sv = *(const short4*)&srow[jq*4];
      #pragma unroll
      for (int u = 0; u < 4; ++u) {
        float s = bf2f((&sv.x)[u]);
        int j = h*64 + jq*4 + u;
        a0 = fmaf(s, x0[j], a0);
        a1 = fmaf(s, x1[j], a1);
      }
    }
    a0 += __shfl_xor(a0, 1);
    a1 += __shfl_xor(a1, 1);
    __syncthreads();
    if (h == 0) {
      x0[i] = a0 + ((i == c0) ? 1.f : 0.f);
      x1[i] = a1 + ((i == c1) ? 1.f : 0.f);
    }
    __syncthreads();
  }
  if (tid < 128) {
    PTmIT[c0*128 + tid] = (short)f2bf(2.f*x0[tid] - ((tid == c0) ? 2.f : 0.f));
  } else {
    int t = tid - 128;
    PTmIT[c1*128 + t] = (short)f2bf(2.f*x1[t] - ((t == c1) ? 2.f : 0.f));
  }
  if (tid < 16) {
    int cc = tid >> 3, g = tid & 7;
    const float* xv = cc ? x1 : x0;
    int c = cc ? c1 : c0;
    float acc = 0.f;
    #pragma unroll 8
    for (int j = 0; j < 128; ++j) acc = fmaf(xv[j], Ww1[j*8 + g], acc);
    PW[c*8 + g] = 2.f*acc - Ww1[c*8 + g];
  }
}

// ---------------------------------------------------------------------------
// mega: persistent kernel. 256 blocks x 512 threads; block owns 128 rows.
// P1 qkv+stats -> gridbar -> P2 BN/rot/rope/proj/g1 -> gridbar -> P3 gate2.
// No cross-block plain-memory reads inside (XCD L2 non-coherence): all
// cross-block flow is device-scope atomics; hstat is a separate dispatch.
__global__ __launch_bounds__(512, 2) void mega(
    const float* __restrict__ feat, const float* __restrict__ coord,
    const short* __restrict__ WqT, const short* __restrict__ WkT, const short* __restrict__ WvT,
    const short* __restrict__ PTmIT, const short* __restrict__ Wg1T,
    const float* __restrict__ bq, const float* __restrict__ bk, const float* __restrict__ bv,
    const float* __restrict__ gq, const float* __restrict__ bnq,
    const float* __restrict__ gk, const float* __restrict__ bnk,
    const float* __restrict__ Wg1, const float* __restrict__ bg1,
    const float* __restrict__ PW, const float* __restrict__ bw1,
    const float* __restrict__ ggm, const float* __restrict__ bng,
    const float* __restrict__ Wg2, const float* __restrict__ bg2,
    float* __restrict__ Vv, float* __restrict__ qw, float* __restrict__ kw,
    float* __restrict__ g1, float* __restrict__ gate,
    float* __restrict__ statq, float* __restrict__ statk,
    float* __restrict__ statg1,
    unsigned* __restrict__ umaxp, unsigned* __restrict__ umaxn,
    unsigned* __restrict__ bar)
{
  __shared__ __align__(16) char reg0[34816];  // Bfull / bnS / xs-half fp32[64][132]
  __shared__ __align__(16) char reg1[18432];  // Bh / gpart / pws / w2s
  __shared__ float caq[128], cbq[128], cak[128], cbk[128];
  __shared__ float gml[128], gsg[128];
  __shared__ float ssum[2][128], ssq[2][128];
  __shared__ unsigned ump[128], umn[128];

  short* B0  = (short*)reg0;
  float* xs  = (float*)reg0;      // [64][132] fp32 half-tile
  short* Bh  = (short*)reg1;
  float* r1f = (float*)reg1;      // gpart / pws / w2s overlays

  int tid = threadIdx.x;
  int row0 = blockIdx.x * 128;
  int seg = blockIdx.x >> 6;
  int lane = tid & 63, w = tid >> 6;        // 8 waves
  int l15 = lane & 15, quad = lane >> 4;
  const float invn = 1.f / 32768.f;

  if (tid < 128) {
    ssum[0][tid] = 0.f; ssq[0][tid] = 0.f;
    ssum[1][tid] = 0.f; ssq[1][tid] = 0.f;
    ump[tid] = 0u; umn[tid] = 0u;
  }
  // A-frags for this wave's 16 rows (held in regs all kernel)
  bf16x8 af[4];
  {
    const float4* f4 = (const float4*)feat;
    #pragma unroll
    for (int ks = 0; ks < 4; ++ks) {
      long base = (long)(row0 + w*16 + l15)*32 + ks*8 + quad*2;
      af[ks] = pack_bf8(f4[base], f4[base + 1]);
    }
  }
  // ===== P1: qkv =====
  stageB512(B0, WqT, tid);
  __syncthreads();
  f32x4 linq[8];
  gemm8_lds(B0, af, linq, l15, quad);
  #pragma unroll
  for (int nt = 0; nt < 8; ++nt) {
    int col = nt*16 + l15;
    float bb = bq[col];
    float s = 0.f, s2 = 0.f, mx = -1e30f, mn = 1e30f;
    #pragma unroll
    for (int r = 0; r < 4; ++r) {
      float v = linq[nt][r] + bb;
      linq[nt][r] = v;
      s += v; s2 = fmaf(v, v, s2); mx = fmaxf(mx, v); mn = fminf(mn, v);
    }
    s += __shfl_xor(s, 16); s += __shfl_xor(s, 32);
    s2 += __shfl_xor(s2, 16); s2 += __shfl_xor(s2, 32);
    mx = fmaxf(mx, __shfl_xor(mx, 16)); mx = fmaxf(mx, __shfl_xor(mx, 32));
    mn = fminf(mn, __shfl_xor(mn, 16)); mn = fminf(mn, __shfl_xor(mn, 32));
    if (lane < 16) {
      atomicAdd(&ssum[0][col], s); atomicAdd(&ssq[0][col], s2);
      atomicMax(&ump[col], fenc(mx)); atomicMax(&umn[col], fenc(-mn));
    }
  }
  __syncthreads();
  stageB512(B0, WkT, tid);
  __syncthreads();
  f32x4 link[8];
  gemm8_lds(B0, af, link, l15, quad);
  #pragma unroll
  for (int nt = 0; nt < 8; ++nt) {
    int col = nt*16 + l15;
    float bb = bk[col];
    float s = 0.f, s2 = 0.f;
    #pragma unroll
    for (int r = 0; r < 4; ++r) {
      float v = link[nt][r] + bb;
      link[nt][r] = v;
      s += v; s2 = fmaf(v, v, s2);
    }
    s += __shfl_xor(s, 16); s += __shfl_xor(s, 32);
    s2 += __shfl_xor(s2, 16); s2 += __shfl_xor(s2, 32);
    if (lane < 16) { atomicAdd(&ssum[1][col], s); atomicAdd(&ssq[1][col], s2); }
  }
  __syncthreads();
  stageB512(B0, WvT, tid);
  __syncthreads();
  {
    f32x4 vv[8];
    gemm8_lds(B0, af, vv, l15, quad);
    #pragma unroll
    for (int nt = 0; nt < 8; ++nt) {
      int col = nt*16 + l15;
      float bb = bv[col];
      #pragma unroll
      for (int r = 0; r < 4; ++r) {
        int row = row0 + w*16 + quad*4 + r;
        Vv[(long)row*128 + col] = vv[nt][r] + bb;
      }
    }
  }
  __syncthreads();
  if (tid < 128) {
    atomicAdd(&statq[tid], ssum[0][tid]); atomicAdd(&statq[128 + tid], ssq[0][tid]);
    atomicAdd(&statk[tid], ssum[1][tid]); atomicAdd(&statk[128 + tid], ssq[1][tid]);
    atomicMax(&umaxp[seg*128 + tid], ump[tid]);
    atomicMax(&umaxn[seg*128 + tid], umn[tid]);
  }
  gridbar(bar + 0, NBLK);

  // ===== P2: BN + rot + g1 + rope + projections =====
  if (tid < 128) {
    float m = statq[tid]*invn, vv = fmaf(-m, m, statq[128 + tid]*invn);
    float a = rsqrtf(vv + 1e-5f) * gq[tid];
    float b = fmaf(-m, a, bnq[tid]);
    caq[tid] = a; cbq[tid] = b;
    float mx = fdec(umaxp[seg*128 + tid]);
    float mn = -fdec(umaxn[seg*128 + tid]);
    gml[tid] = fmaxf(0.f, fmaxf(fmaf(a, mx, b), fmaf(a, mn, b)));
    m = statk[tid]*invn; vv = fmaf(-m, m, statk[128 + tid]*invn);
    a = rsqrtf(vv + 1e-5f) * gk[tid];
    cak[tid] = a; cbk[tid] = fmaf(-m, a, bnk[tid]);
    ssum[0][tid] = 0.f; ssq[0][tid] = 0.f;   // reuse for g1 stats
  }
  __syncthreads();
  // gseg partials (coalesced across c) into r1f[0..511]
  {
    int c = tid & 127, jq = tid >> 7;
    float acc = 0.f;
    #pragma unroll 8
    for (int j = 0; j < 32; ++j) {
      int jj = jq*32 + j;
      acc = fmaf(gml[jj], Wg1[(128 + jj)*128 + c], acc);
    }
    r1f[jq*128 + c] = acc;
  }
  // bnq in regs + bf16 A-layout round-trip
  float bnl[32];
  #pragma unroll
  for (int nt = 0; nt < 8; ++nt) {
    int col = nt*16 + l15;
    float A = caq[col], B = cbq[col];
    #pragma unroll
    for (int r = 0; r < 4; ++r) {
      float v = fmaxf(0.f, fmaf(A, linq[nt][r], B));
      bnl[nt*4 + r] = v;
      B0[(w*16 + quad*4 + r)*LSTR + col] = (short)f2bf(v);
    }
  }
  __syncthreads();
  if (tid < 128)
    gsg[tid] = r1f[tid] + r1f[128 + tid] + r1f[256 + tid] + r1f[384 + tid] + bg1[tid];
  bf16x8 af2[4];
  #pragma unroll
  for (int ks = 0; ks < 4; ++ks)
    af2[ks] = *(bf16x8*)&B0[(w*16 + l15)*LSTR + ks*32 + quad*8];
  __syncthreads();   // bnS dead; gpart dead; gsg ready
  f32x4 accv[8], accw[8];
  #pragma unroll
  for (int nt = 0; nt < 8; ++nt) { accv[nt] = f32x4{0,0,0,0}; accw[nt] = f32x4{0,0,0,0}; }
  stageBh(Bh, PTmIT, 0, tid);  __syncthreads();
  gemmHalf(Bh, af2, accv, 0, l15, quad);  __syncthreads();
  stageBh(Bh, PTmIT, 64, tid); __syncthreads();
  gemmHalf(Bh, af2, accv, 1, l15, quad);  __syncthreads();
  stageBh(Bh, Wg1T, 0, tid);   __syncthreads();
  gemmHalf(Bh, af2, accw, 0, l15, quad);  __syncthreads();
  stageBh(Bh, Wg1T, 64, tid);  __syncthreads();
  gemmHalf(Bh, af2, accw, 1, l15, quad);
  // g1 epilogue
  #pragma unroll
  for (int nt = 0; nt < 8; ++nt) {
    int col = nt*16 + l15;
    float gsv = gsg[col];
    float s = 0.f, s2 = 0.f;
    #pragma unroll
    for (int r = 0; r < 4; ++r) {
      float v = accw[nt][r] + gsv;
      int row = row0 + w*16 + quad*4 + r;
      g1[(long)row*128 + col] = v;
      s += v; s2 = fmaf(v, v, s2);
    }
    s += __shfl_xor(s, 16); s += __shfl_xor(s, 32);
    s2 += __shfl_xor(s2, 16); s2 += __shfl_xor(s2, 32);
    if (lane < 16) { atomicAdd(&ssum[0][col], s); atomicAdd(&ssq[0][col], s2); }
  }
  __syncthreads();   // Bh reads done -> pws overlay OK
  // pws
  r1f[tid] = PW[tid]; r1f[512 + tid] = PW[512 + tid];
  // q: xs halves (fp32, exact diag), rope, project
  #pragma unroll
  for (int hh = 0; hh < 2; ++hh) {
    if ((w >> 2) == hh) {
      int wl = w & 3;
      #pragma unroll
      for (int nt = 0; nt < 8; ++nt) {
        int col = nt*16 + l15;
        #pragma unroll
        for (int r = 0; r < 4; ++r)
          xs[(wl*16 + quad*4 + r)*132 + col] = accv[nt][r] + bnl[nt*4 + r];
      }
    }
    __syncthreads();
    #pragma unroll
    for (int it = 0; it < 8; ++it) {
      int idx = it*512 + tid;
      int r = idx >> 6, s = idx & 63;
      if (s < 63) {
        int a3 = s / 21, j = s - a3*21;
        int cr = a3*42 + j;
        float invf = exp2f((float)(2*j) * (-13.287712379549449f / 42.f));
        float ang = coord[(row0 + hh*64 + r)*3 + a3] * (2.0f * invf);
        float sn, co; sincosf(ang, &sn, &co);
        float fr = xs[r*132 + cr], fi = xs[r*132 + cr + 21];
        xs[r*132 + cr]      = fr*co - fi*sn;
        xs[r*132 + cr + 21] = fr*sn + fi*co;
      }
    }
    __syncthreads();
    {
      int r2 = tid >> 3, g = tid & 7;
      float a0 = 0.f, a1 = 0.f, a2 = 0.f, a3 = 0.f;
      #pragma unroll 8
      for (int i = 0; i < 128; i += 4) {
        float4 xv = *(const float4*)&xs[r2*132 + i];
        a0 = fmaf(xv.x, r1f[(i+0)*8 + g], a0);
        a1 = fmaf(xv.y, r1f[(i+1)*8 + g], a1);
        a2 = fmaf(xv.z, r1f[(i+2)*8 + g], a2);
        a3 = fmaf(xv.w, r1f[(i+3)*8 + g], a3);
      }
      qw[(long)(row0 + hh*64 + r2)*8 + g] = (a0 + a1) + (a2 + a3);
    }
    __syncthreads();
  }
  // k: bn, round-trip, rot, xs halves, rope, project (+bw1)
  #pragma unroll
  for (int nt = 0; nt < 8; ++nt) {
    int col = nt*16 + l15;
    float A = cak[col], B = cbk[col];
    #pragma unroll
    for (int r = 0; r < 4; ++r) {
      float v = fmaxf(0.f, fmaf(A, link[nt][r], B));
      bnl[nt*4 + r] = v;
      B0[(w*16 + quad*4 + r)*LSTR + col] = (short)f2bf(v);
    }
  }
  __syncthreads();
  #pragma unroll
  for (int ks = 0; ks < 4; ++ks)
    af2[ks] = *(bf16x8*)&B0[(w*16 + l15)*LSTR + ks*32 + quad*8];
  __syncthreads();
  #pragma unroll
  for (int nt = 0; nt < 8; ++nt) accv[nt] = f32x4{0,0,0,0};
  stageBh(Bh, PTmIT, 0, tid);  __syncthreads();
  gemmHalf(Bh, af2, accv, 0, l15, quad);  __syncthreads();
  stageBh(Bh, PTmIT, 64, tid); __syncthreads();
  gemmHalf(Bh, af2, accv, 1, l15, quad);
  __syncthreads();   // Bh reads done
  r1f[tid] = PW[tid]; r1f[512 + tid] = PW[512 + tid];
  #pragma unroll
  for (int hh = 0; hh < 2; ++hh) {
    if ((w >> 2) == hh) {
      int wl = w & 3;
      #pragma unroll
      for (int nt = 0; nt < 8; ++nt) {
        int col = nt*16 + l15;
        #pragma unroll
        for (int r = 0; r < 4; ++r)
          xs[(wl*16 + quad*4 + r)*132 + col] = accv[nt][r] + bnl[nt*4 + r];
      }
    }
    __syncthreads();
    #pragma unroll
    for (int it = 0; it < 8; ++it) {
      int idx = it*512 + tid;
      int r = idx >> 6, s = idx & 63;
      if (s < 63) {
        int a3 = s / 21, j = s - a3*21;
        int cr = a3*42 + j;
        float invf = exp2f((float)(2*j) * (-13.287712379549449f / 42.f));
        float ang = coord[(row0 + hh*64 + r)*3 + a3] * (2.0f * invf);
        float sn, co; sincosf(ang, &sn, &co);
        float fr = xs[r*132 + cr], fi = xs[r*132 + cr + 21];
        xs[r*132 + cr]      = fr*co - fi*sn;
        xs[r*132 + cr + 21] = fr*sn + fi*co;
      }
    }
    __syncthreads();
    {
      int r2 = tid >> 3, g = tid & 7;
      float a0 = 0.f, a1 = 0.f, a2 = 0.f, a3 = 0.f;
      #pragma unroll 8
      for (int i = 0; i < 128; i += 4) {
        float4 xv = *(const float4*)&xs[r2*132 + i];
        a0 = fmaf(xv.x, r1f[(i+0)*8 + g], a0);
        a1 = fmaf(xv.y, r1f[(i+1)*8 + g], a1);
        a2 = fmaf(xv.z, r1f[(i+2)*8 + g], a2);
        a3 = fmaf(xv.w, r1f[(i+3)*8 + g], a3);
      }
      kw[(long)(row0 + hh*64 + r2)*8 + g] = (a0 + a1) + (a2 + a3) + bw1[g];
    }
    __syncthreads();
  }
  if (tid < 128) {
    atomicAdd(&statg1[tid], ssum[0][tid]);
    atomicAdd(&statg1[128 + tid], ssq[0][tid]);
  }
  gridbar(bar + 1, NBLK);

  // ===== P3: gate2 (block-local g1 + atomic-finalized statg1 only) =====
  if (tid < 128) {
    float m = statg1[tid]*invn, v = fmaf(-m, m, statg1[128 + tid]*invn);
    float a = rsqrtf(v + 1e-5f) * ggm[tid];
    caq[tid] = a; cbq[tid] = fmaf(-m, a, bng[tid]);
  }
  r1f[tid] = Wg2[tid]; r1f[512 + tid] = Wg2[512 + tid];   // w2s
  __syncthreads();
  #pragma unroll
  for (int hh = 0; hh < 2; ++hh) {
    #pragma unroll
    for (int it = 0; it < 4; ++it) {
      int q = it*512 + tid; int r = q >> 5, c4 = q & 31;
      *(float4*)&xs[r*132 + c4*4] = *(const float4*)&g1[(long)(row0 + hh*64 + r)*128 + c4*4];
    }
    __syncthreads();
    {
      int r2 = tid >> 3, g = tid & 7;
      float acc = bg2[g];
      #pragma unroll 8
      for (int c = 0; c < 128; ++c) {
        float act = fmaxf(0.f, fmaf(caq[c], xs[r2*132 + c], cbq[c]));
        acc = fmaf(act, r1f[c*8 + g], acc);
      }
      gate[(long)(row0 + hh*64 + r2)*8 + g] = 1.f / (1.f + expf(-acc));
    }
    __syncthreads();
  }
}

// ---------------------------------------------------------------------------
// hstat: separate dispatch (kernel boundary = cross-XCD kw/qw visibility).
__global__ __launch_bounds__(256) void hstat(const float* __restrict__ kw, const float* __restrict__ qw,
                                             const int* __restrict__ ref, float* __restrict__ stath)
{
  int tid = threadIdx.x;
  long base = (long)blockIdx.x * 4096;
  float s = 0.f, sq = 0.f;
  for (int it = 0; it < 16; ++it) {
    long idx = base + it*256 + tid;
    int n = (int)(idx >> 7); int kk = (int)((idx >> 3) & 15); int g = (int)(idx & 7);
    int r = ref[n*16 + kk];
    float h = kw[(long)r*8 + g] - qw[(long)n*8 + g];
    s += h; sq = fmaf(h, h, sq);
  }
  __shared__ float red[256];
  red[tid] = s; __syncthreads();
  for (int d = 128; d >= 8; d >>= 1) { if (tid < d) red[tid] += red[tid + d]; __syncthreads(); }
  if (tid < 8) atomicAdd(&stath[tid], red[tid]);
  __syncthreads();
  red[tid] = sq; __syncthreads();
  for (int d = 128; d >= 8; d >>= 1) { if (tid < d) red[tid] += red[tid + d]; __syncthreads(); }
  if (tid < 8) atomicAdd(&stath[8 + tid], red[tid]);
}

// ---------------------------------------------------------------------------
// attn_out: h recompute, BN+relu, @Ww2, gate, softmax, V gather
__global__ __launch_bounds__(256) void attn_out(const float* __restrict__ qw, const float* __restrict__ kw,
                                                const float* __restrict__ stath,
                                                const float* __restrict__ gw, const float* __restrict__ bnw,
                                                const float* __restrict__ Ww2, const float* __restrict__ bw2,
                                                const float* __restrict__ gate, const int* __restrict__ ref,
                                                const float* __restrict__ v, float* __restrict__ out)
{
  __shared__ float sm1[2][16][9];
  __shared__ float sm2[2][16][9];
  __shared__ int   smr[2][16];
  int tid = threadIdx.x; int rh = tid >> 7, t = tid & 127;
  int n = blockIdx.x * 2 + rh;
  int kk = t >> 3, g = t & 7;
  if (t < 16) smr[rh][t] = ref[n*16 + t];
  __syncthreads();
  const float invnk = 1.f / 524288.f;
  float m0 = stath[g]*invnk, v0 = fmaf(-m0, m0, stath[8 + g]*invnk);
  float aw = rsqrtf(v0 + 1e-5f) * gw[g];
  float bw = fmaf(-m0, aw, bnw[g]);
  int rr = smr[rh][kk];
  float h = kw[(long)rr*8 + g] - qw[(long)n*8 + g];
  sm1[rh][kk][g] = fmaxf(0.f, fmaf(h, aw, bw));
  __syncthreads();
  float acc = bw2[g];
  #pragma unroll
  for (int g2 = 0; g2 < 8; ++g2) acc = fmaf(sm1[rh][kk][g2], Ww2[g2*8 + g], acc);
  float refined = acc * (1.f + gate[(long)n*8 + g]);
  sm2[rh][kk][g] = refined;
  __syncthreads();
  float mx = -1e30f;
  #pragma unroll
  for (int k2 = 0; k2 < 16; ++k2) mx = fmaxf(mx, sm2[rh][k2][g]);
  float e = expf(refined - mx);
  sm1[rh][kk][g] = e;
  __syncthreads();
  float ssum = 0.f;
  #pragma unroll
  for (int k2 = 0; k2 < 16; ++k2) ssum += sm1[rh][k2][g];
  float mask = ((rr + 1) > 0) ? 1.f : (((rr + 1) == 0) ? 0.f : -1.f);
  float attn = e / ssum * mask;
  sm2[rh][kk][g] = attn;
  __syncthreads();
  float o = 0.f;
  #pragma unroll
  for (int k2 = 0; k2 < 16; ++k2) {
    o = fmaf(v[(long)smr[rh][k2]*128 + t], sm2[rh][k2][t >> 4], o);
  }
  out[(long)n*128 + t] = o;
}

// ---------------------------------------------------------------------------
extern "C" void kernel_launch(void* const* d_in, const int* in_sizes, int n_in,
                              void* d_out, int out_size, void* d_ws, size_t ws_size,
                              hipStream_t stream)
{
  const float* feat  = (const float*)d_in[0];
  const float* coord = (const float*)d_in[1];
  const int*   ref   = (const int*)d_in[2];
  const float* Wq  = (const float*)d_in[4];
  const float* bq  = (const float*)d_in[5];
  const float* gq  = (const float*)d_in[6];
  const float* bnq = (const float*)d_in[7];
  const float* Wk  = (const float*)d_in[8];
  const float* bk  = (const float*)d_in[9];
  const float* gk  = (const float*)d_in[10];
  const float* bnk = (const float*)d_in[11];
  const float* Wv  = (const float*)d_in[12];
  const float* bv  = (const float*)d_in[13];
  const float* Sp  = (const float*)d_in[14];
  const float* Ww1 = (const float*)d_in[15];
  const float* bw1 = (const float*)d_in[16];
  const float* gw  = (const float*)d_in[17];
  const float* bnw = (const float*)d_in[18];
  const float* Ww2 = (const float*)d_in[19];
  const float* bw2 = (const float*)d_in[20];
  const float* Wg1 = (const float*)d_in[21];
  const float* bg1 = (const float*)d_in[22];
  const float* ggm = (const float*)d_in[23];
  const float* bng = (const float*)d_in[24];
  const float* Wg2 = (const float*)d_in[25];
  const float* bg2 = (const float*)d_in[26];
  float* out = (float*)d_out;

  float* W = (float*)d_ws;
  float* PW = W + OF_PW;
  short* WqT   = (short*)(W + OF_WQT);
  short* WkT   = (short*)(W + OF_WKT);
  short* WvT   = (short*)(W + OF_WVT);
  short* Wg1T  = (short*)(W + OF_WG1T);
  short* PTmIT = (short*)(W + OF_PTMIT);
  float* G1 = W + OF_G1;
  float* Vv = W + OF_V;

  // 1: Cayley + weight transposes + zero stats/barrier
  cayley<<<81, 256, 0, stream>>>(Sp, Ww1, Wq, Wk, Wv, Wg1,
                                 WqT, WkT, WvT, Wg1T, PTmIT, PW, W + OF_STATQ);
  // 2: persistent fused qkv -> BN/rot/rope/proj/g1 -> gate2
  mega<<<NBLK, 512, 0, stream>>>(feat, coord,
                                 WqT, WkT, WvT, PTmIT, Wg1T,
                                 bq, bk, bv, gq, bnq, gk, bnk,
                                 Wg1, bg1, PW, bw1, ggm, bng, Wg2, bg2,
                                 Vv, W + OF_QW, W + OF_KW, G1, W + OF_GATE,
                                 W + OF_STATQ, W + OF_STATK, W + OF_STATG1,
                                 (unsigned*)(W + OF_UMAXP), (unsigned*)(W + OF_UMAXN),
                                 (unsigned*)(W + OF_BAR));
  // 3: hstat (kernel boundary = cross-XCD kw visibility)
  hstat<<<1024, 256, 0, stream>>>(W + OF_KW, W + OF_QW, ref, W + OF_STATH);
  // 4: final attention + V gather
  attn_out<<<16384, 256, 0, stream>>>(W + OF_QW, W + OF_KW, W + OF_STATH, gw, bnw, Ww2, bw2,
                                      W + OF_GATE, ref, Vv, out);
}